// Round 1
// baseline (182.779 us; speedup 1.0000x reference)
//
#include <hip/hip_runtime.h>
#include <hip/hip_bf16.h>

// Problem constants: B=2, T=512, C=256, HID=1024. Rows = B*T = 1024.
// Reference collapses (attention branch is *0.0) to:
//   xp  = x + bp
//   h2  = LN(xp, g2, b2)
//   out = xp + relu(h2 @ W1.T + bf1) @ W2.T + bf2

#define LN_EPS 1e-5f

__global__ __launch_bounds__(256) void ln_kernel(
    const float* __restrict__ x, const float* __restrict__ bp,
    const float* __restrict__ g2, const float* __restrict__ b2,
    float* __restrict__ xp, float* __restrict__ h2) {
  const int row = blockIdx.x;      // 0..1023
  const int tid = threadIdx.x;     // 0..255
  const int idx = (row << 8) + tid;
  float v = x[idx] + bp[tid];
  float s = v, s2 = v * v;
  #pragma unroll
  for (int off = 32; off > 0; off >>= 1) {
    s  += __shfl_down(s, off);
    s2 += __shfl_down(s2, off);
  }
  __shared__ float red[8];
  const int wave = tid >> 6, lane = tid & 63;
  if (lane == 0) { red[wave] = s; red[4 + wave] = s2; }
  __syncthreads();
  const float ts  = red[0] + red[1] + red[2] + red[3];
  const float ts2 = red[4] + red[5] + red[6] + red[7];
  const float mu   = ts * (1.0f / 256.0f);
  const float var  = ts2 * (1.0f / 256.0f) - mu * mu;
  const float rstd = rsqrtf(var + LN_EPS);
  xp[idx] = v;
  h2[idx] = (v - mu) * rstd * g2[tid] + b2[tid];
}

// NT GEMM: C[m][n] = sum_k A[m][k] * B[n][k]  (both row-major, K contiguous)
// LDS tiles stored transposed [BK][BM+4]: pad=4 keeps float4 reads 16B-aligned
// and bank aliasing <= 2-way (free on gfx950).
template<int BM, int BN, int BK, int TM, int TN, bool RELU>
__global__ __launch_bounds__(256) void gemm_nt(
    const float* __restrict__ A, const float* __restrict__ Bmat,
    const float* __restrict__ bias, const float* __restrict__ resid,
    float* __restrict__ C, int M, int N, int K) {
  __shared__ float As[BK][BM + 4];
  __shared__ float Bs[BK][BN + 4];
  constexpr int NTX = BN / TN;
  constexpr int NTY = BM / TM;
  static_assert(NTX * NTY == 256, "block must be 256 threads");
  const int tid = threadIdx.x;
  const int tx = tid % NTX, ty = tid / NTX;
  const int bm = blockIdx.y * BM, bn = blockIdx.x * BN;

  float acc[TM][TN] = {};

  for (int k0 = 0; k0 < K; k0 += BK) {
    // stage A tile: BM x BK, one float4 per iteration per thread
    constexpr int A_F4 = BM * BK / 4;
    #pragma unroll
    for (int i = tid; i < A_F4; i += 256) {
      const int r  = i / (BK / 4);
      const int c4 = i % (BK / 4);
      const float4 v = *reinterpret_cast<const float4*>(
          &A[(size_t)(bm + r) * K + k0 + c4 * 4]);
      As[c4 * 4 + 0][r] = v.x; As[c4 * 4 + 1][r] = v.y;
      As[c4 * 4 + 2][r] = v.z; As[c4 * 4 + 3][r] = v.w;
    }
    constexpr int B_F4 = BN * BK / 4;
    #pragma unroll
    for (int i = tid; i < B_F4; i += 256) {
      const int r  = i / (BK / 4);
      const int c4 = i % (BK / 4);
      const float4 v = *reinterpret_cast<const float4*>(
          &Bmat[(size_t)(bn + r) * K + k0 + c4 * 4]);
      Bs[c4 * 4 + 0][r] = v.x; Bs[c4 * 4 + 1][r] = v.y;
      Bs[c4 * 4 + 2][r] = v.z; Bs[c4 * 4 + 3][r] = v.w;
    }
    __syncthreads();

    #pragma unroll
    for (int kk = 0; kk < BK; ++kk) {
      float a[TM], b[TN];
      #pragma unroll
      for (int i = 0; i < TM; ++i) a[i] = As[kk][ty * TM + i];
      #pragma unroll
      for (int j = 0; j < TN; ++j) b[j] = Bs[kk][tx * TN + j];
      #pragma unroll
      for (int i = 0; i < TM; ++i)
        #pragma unroll
        for (int j = 0; j < TN; ++j)
          acc[i][j] = fmaf(a[i], b[j], acc[i][j]);
    }
    __syncthreads();
  }

  #pragma unroll
  for (int i = 0; i < TM; ++i) {
    const int m = bm + ty * TM + i;
    #pragma unroll
    for (int j = 0; j < TN; ++j) {
      const int n = bn + tx * TN + j;
      float v = acc[i][j] + bias[n];
      if (RELU) {
        v = fmaxf(v, 0.0f);
      } else {
        v += resid[(size_t)m * N + n];
      }
      C[(size_t)m * N + n] = v;
    }
  }
}

extern "C" void kernel_launch(void* const* d_in, const int* in_sizes, int n_in,
                              void* d_out, int out_size, void* d_ws, size_t ws_size,
                              hipStream_t stream) {
  // setup_inputs order: x, Wt, Wp, bp, g1, b1, g2, b2, W1, bf1, W2, bf2
  const float* x   = (const float*)d_in[0];
  const float* bp  = (const float*)d_in[3];
  const float* g2  = (const float*)d_in[6];
  const float* b2  = (const float*)d_in[7];
  const float* W1  = (const float*)d_in[8];
  const float* bf1 = (const float*)d_in[9];
  const float* W2  = (const float*)d_in[10];
  const float* bf2 = (const float*)d_in[11];
  float* out = (float*)d_out;

  constexpr int ROWS = 1024;   // B*T
  constexpr int Cdim = 256;
  constexpr int HID  = 1024;

  float* xp = (float*)d_ws;            // ROWS*Cdim
  float* h2 = xp + ROWS * Cdim;        // ROWS*Cdim
  float* H  = h2 + ROWS * Cdim;        // ROWS*HID (post-relu hidden)
  // total ws use: 6 MB

  ln_kernel<<<ROWS, 256, 0, stream>>>(x, bp, g2, b2, xp, h2);

  // H = relu(h2 @ W1.T + bf1): M=1024, N=1024, K=256
  gemm_nt<64, 64, 16, 4, 4, true><<<dim3(HID / 64, ROWS / 64), 256, 0, stream>>>(
      h2, W1, bf1, nullptr, H, ROWS, HID, Cdim);

  // out = xp + (H @ W2.T + bf2): M=1024, N=256, K=1024
  gemm_nt<64, 32, 32, 4, 2, false><<<dim3(Cdim / 32, ROWS / 64), 256, 0, stream>>>(
      H, W2, bf2, xp, out, ROWS, Cdim, HID);
}

// Round 2
// 119.949 us; speedup vs baseline: 1.5238x; 1.5238x over previous
//
#include <hip/hip_runtime.h>

// B=2, T=512, C=256, HID=1024. ROWS=1024.
// Reference collapses (attn branch *0.0) to:
//   xp = x + bp;  h2 = LN(xp,g2,b2);  out = xp + relu(h2@W1.T+bf1)@W2.T + bf2
// bf16 MFMA path (absmax threshold 0.101 permits bf16 compute).

typedef short bf8_t __attribute__((ext_vector_type(8)));  // 8 bf16 in 4 VGPRs
typedef float f4_t  __attribute__((ext_vector_type(4)));

__device__ inline unsigned short f2bf(float f) {  // round-to-nearest-even
  unsigned u = __float_as_uint(f);
  u += 0x7fffu + ((u >> 16) & 1u);
  return (unsigned short)(u >> 16);
}

// ---- prep: blocks [0,1024) = LayerNorm rows; [1024,1536) = W1/W2 -> bf16 ----
__global__ __launch_bounds__(256) void prep_kernel(
    const float* __restrict__ x, const float* __restrict__ bp,
    const float* __restrict__ g2, const float* __restrict__ b2,
    const float* __restrict__ W1, const float* __restrict__ W2,
    float* __restrict__ xp, unsigned short* __restrict__ h2,
    unsigned short* __restrict__ w1b, unsigned short* __restrict__ w2b) {
  const int b = blockIdx.x, t = threadIdx.x;
  if (b < 1024) {
    const int idx = (b << 8) + t;
    float v = x[idx] + bp[t];
    float s = v, s2 = v * v;
    #pragma unroll
    for (int off = 32; off > 0; off >>= 1) {
      s  += __shfl_down(s, off);
      s2 += __shfl_down(s2, off);
    }
    __shared__ float red[8];
    const int wave = t >> 6, lane = t & 63;
    if (lane == 0) { red[wave] = s; red[4 + wave] = s2; }
    __syncthreads();
    const float ts  = red[0] + red[1] + red[2] + red[3];
    const float ts2 = red[4] + red[5] + red[6] + red[7];
    const float mu   = ts * (1.0f / 256.0f);
    const float var  = ts2 * (1.0f / 256.0f) - mu * mu;
    const float rstd = rsqrtf(var + 1e-5f);
    xp[idx] = v;
    h2[idx] = f2bf((v - mu) * rstd * g2[t] + b2[t]);
  } else {
    const int e = ((b - 1024) << 10) + (t << 2);  // 4 floats per thread
    const float* src; unsigned short* dst;
    if (e < 262144) { src = W1 + e;          dst = w1b + e; }
    else            { src = W2 + (e - 262144); dst = w2b + (e - 262144); }
    const float4 v = *(const float4*)src;
    ushort4 o;
    o.x = f2bf(v.x); o.y = f2bf(v.y); o.z = f2bf(v.z); o.w = f2bf(v.w);
    *(ushort4*)dst = o;
  }
}

// ---- GEMM1: H[1024][1024] = relu(h2[1024][256] @ W1[1024][256]^T + bf1) ----
// 64x64 tile, BK=128, 4 waves 2x2, wave=32x32 via 2x2 mfma_16x16x32 frags.
// LDS row stride 136 ush (=272B): frag-read bank aliasing 2-way (free).
__global__ __launch_bounds__(256) void gemm1_kernel(
    const unsigned short* __restrict__ A,   // h2, K-major [1024][256]
    const unsigned short* __restrict__ Bm,  // w1b, K-major [1024][256]
    const float* __restrict__ bias,         // bf1[1024]
    unsigned short* __restrict__ H) {       // [1024][1024] bf16
  __shared__ unsigned short As[64 * 136];
  __shared__ unsigned short Bs[64 * 136];
  const int tid = threadIdx.x;
  const int bm = blockIdx.y << 6, bn = blockIdx.x << 6;
  const int wave = tid >> 6, lane = tid & 63;
  const int wy = (wave >> 1) << 5, wx = (wave & 1) << 5;
  const int quad = lane >> 4, l16 = lane & 15;
  f4_t acc[2][2] = {};

  for (int kt = 0; kt < 256; kt += 128) {
    #pragma unroll
    for (int c = 0; c < 4; ++c) {
      const int ch = (c << 8) + tid;          // 1024 chunks of 8 bf16
      const int r = ch >> 4, cc = ch & 15;
      *(uint4*)&As[r * 136 + (cc << 3)] =
          *(const uint4*)&A[((bm + r) << 8) + kt + (cc << 3)];
      *(uint4*)&Bs[r * 136 + (cc << 3)] =
          *(const uint4*)&Bm[((bn + r) << 8) + kt + (cc << 3)];
    }
    __syncthreads();
    #pragma unroll
    for (int ks = 0; ks < 4; ++ks) {
      bf8_t af[2], bv[2];
      #pragma unroll
      for (int i = 0; i < 2; ++i)
        af[i] = *(const bf8_t*)&As[(wy + (i << 4) + l16) * 136 + (ks << 5) + (quad << 3)];
      #pragma unroll
      for (int j = 0; j < 2; ++j)
        bv[j] = *(const bf8_t*)&Bs[(wx + (j << 4) + l16) * 136 + (ks << 5) + (quad << 3)];
      #pragma unroll
      for (int i = 0; i < 2; ++i)
        #pragma unroll
        for (int j = 0; j < 2; ++j)
          acc[i][j] = __builtin_amdgcn_mfma_f32_16x16x32_bf16(af[i], bv[j], acc[i][j], 0, 0, 0);
    }
    __syncthreads();
  }

  #pragma unroll
  for (int j = 0; j < 2; ++j) {
    const int n = bn + wx + (j << 4) + l16;
    const float bvv = bias[n];
    #pragma unroll
    for (int i = 0; i < 2; ++i) {
      #pragma unroll
      for (int r = 0; r < 4; ++r) {
        const int m = bm + wy + (i << 4) + (quad << 2) + r;
        float v = acc[i][j][r] + bvv;
        v = fmaxf(v, 0.0f);
        H[(m << 10) + n] = f2bf(v);
      }
    }
  }
}

// ---- GEMM2: out[1024][256] = xp + H[1024][1024] @ W2[256][1024]^T + bf2 ----
// 32x32 tile, BK=256, 4 waves 2x2, one 16x16 frag per wave.
__global__ __launch_bounds__(256) void gemm2_kernel(
    const unsigned short* __restrict__ A,   // H, K-major [1024][1024]
    const unsigned short* __restrict__ Bm,  // w2b, K-major [256][1024]
    const float* __restrict__ bias,         // bf2[256]
    const float* __restrict__ resid,        // xp [1024][256] fp32
    float* __restrict__ out) {
  __shared__ unsigned short As[32 * 264];
  __shared__ unsigned short Bs[32 * 264];
  const int tid = threadIdx.x;
  const int bm = blockIdx.y << 5, bn = blockIdx.x << 5;
  const int wave = tid >> 6, lane = tid & 63;
  const int wy = (wave >> 1) << 4, wx = (wave & 1) << 4;
  const int quad = lane >> 4, l16 = lane & 15;
  f4_t acc = {};

  for (int kt = 0; kt < 1024; kt += 256) {
    #pragma unroll
    for (int c = 0; c < 4; ++c) {
      const int ch = (c << 8) + tid;          // 1024 chunks of 8 bf16
      const int r = ch >> 5, cc = ch & 31;
      *(uint4*)&As[r * 264 + (cc << 3)] =
          *(const uint4*)&A[((bm + r) << 10) + kt + (cc << 3)];
      *(uint4*)&Bs[r * 264 + (cc << 3)] =
          *(const uint4*)&Bm[((bn + r) << 10) + kt + (cc << 3)];
    }
    __syncthreads();
    #pragma unroll
    for (int ks = 0; ks < 8; ++ks) {
      const bf8_t af = *(const bf8_t*)&As[(wy + l16) * 264 + (ks << 5) + (quad << 3)];
      const bf8_t bv = *(const bf8_t*)&Bs[(wx + l16) * 264 + (ks << 5) + (quad << 3)];
      acc = __builtin_amdgcn_mfma_f32_16x16x32_bf16(af, bv, acc, 0, 0, 0);
    }
    __syncthreads();
  }

  const int n = bn + wx + l16;
  const float bvv = bias[n];
  #pragma unroll
  for (int r = 0; r < 4; ++r) {
    const int m = bm + wy + (quad << 2) + r;
    out[(m << 8) + n] = acc[r] + bvv + resid[(m << 8) + n];
  }
}

extern "C" void kernel_launch(void* const* d_in, const int* in_sizes, int n_in,
                              void* d_out, int out_size, void* d_ws, size_t ws_size,
                              hipStream_t stream) {
  // inputs: x, Wt, Wp, bp, g1, b1, g2, b2, W1, bf1, W2, bf2
  const float* x   = (const float*)d_in[0];
  const float* bp  = (const float*)d_in[3];
  const float* g2  = (const float*)d_in[6];
  const float* b2  = (const float*)d_in[7];
  const float* W1  = (const float*)d_in[8];
  const float* bf1 = (const float*)d_in[9];
  const float* W2  = (const float*)d_in[10];
  const float* bf2 = (const float*)d_in[11];
  float* out = (float*)d_out;

  float* xp = (float*)d_ws;                          // 1 MB
  unsigned short* h2  = (unsigned short*)(xp + 262144);   // 512 KB
  unsigned short* w1b = h2 + 262144;                      // 512 KB
  unsigned short* w2b = w1b + 262144;                     // 512 KB
  unsigned short* H   = w2b + 262144;                     // 2 MB

  prep_kernel<<<1536, 256, 0, stream>>>(x, bp, g2, b2, W1, W2, xp, h2, w1b, w2b);
  gemm1_kernel<<<dim3(16, 16), 256, 0, stream>>>(h2, w1b, bf1, H);
  gemm2_kernel<<<dim3(8, 32), 256, 0, stream>>>(H, w2b, bf2, xp, out);
}